// Round 8
// baseline (20188.728 us; speedup 1.0000x reference)
//
#include <hip/hip_runtime.h>

#define TSTEPS 8192
#define NDIM   2048
#define NBLK   128
#define NTHR   512
#define RPB    16     // rows per block = NDIM/NBLK

typedef float    f32x4 __attribute__((ext_vector_type(4)));
typedef unsigned u32x4 __attribute__((ext_vector_type(4)));

__device__ __forceinline__ void st_x4_agent(u32x4* p, u32x4 v) {
  asm volatile("global_store_dwordx4 %0, %1, off sc1" :: "v"(p), "v"(v) : "memory");
}

// Park one f32x4 of W in four FIXED AGPRs. Rounds 3-7: the allocator spilled W
// to scratch no matter what (VGPR_Count 48-52 < the 64 W needs), re-loading it
// every step inside the serial dot phase. AGPRs are outside its reach: it never
// touches them without MFMA, and the clobbers force agpr_count=64 allocation.
#define W2A(val, A0, A1, A2, A3) do { const f32x4 _w = (val);                \
  asm volatile("v_accvgpr_write_b32 " A0 ", %0\n\t"                          \
               "v_accvgpr_write_b32 " A1 ", %1\n\t"                          \
               "v_accvgpr_write_b32 " A2 ", %2\n\t"                          \
               "v_accvgpr_write_b32 " A3 ", %3"                              \
               :: "v"(_w.x), "v"(_w.y), "v"(_w.z), "v"(_w.w)                 \
               : A0, A1, A2, A3); } while (0)

#define A2V(dst, A0, A1, A2, A3)                                             \
  asm volatile("v_accvgpr_read_b32 %0, " A0 "\n\t"                           \
               "v_accvgpr_read_b32 %1, " A1 "\n\t"                           \
               "v_accvgpr_read_b32 %2, " A2 "\n\t"                           \
               "v_accvgpr_read_b32 %3, " A3                                  \
               : "=v"((dst).x), "=v"((dst).y), "=v"((dst).z), "=v"((dst).w))

// Depth-2 pipelined poll: two alternating in-flight sc1 loads, wait vmcnt(1)
// -> tag-check interval = latency/2 (was a full serialized round trip).
// Wave-uniform exit; unpack (bf16 high-half mask) + ds_write_b128 done inside.
// Returns the retry counter; >= 2^20 means budget exhausted (caller aborts).
__device__ __forceinline__ unsigned poll_stage(const u32x4* src, unsigned want,
                                               unsigned lds_byte) {
  unsigned cnt;
  asm volatile(
    "s_mov_b32 %[ct], 0\n\t"
    "global_load_dwordx4 v[40:43], %[ad], off sc1\n"
    "Lpoll%=:\n\t"
    "global_load_dwordx4 v[44:47], %[ad], off sc1\n\t"
    "s_waitcnt vmcnt(1)\n\t"
    "v_xor_b32 v48, %[wt], v40\n\t"
    "v_xor_b32 v49, %[wt], v41\n\t"
    "v_or_b32 v48, v48, v49\n\t"
    "v_xor_b32 v49, %[wt], v42\n\t"
    "v_or_b32 v48, v48, v49\n\t"
    "v_xor_b32 v49, %[wt], v43\n\t"
    "v_or_b32 v48, v48, v49\n\t"
    "v_and_b32 v48, 0xffff, v48\n\t"
    "v_cmp_ne_u32 vcc, 0, v48\n\t"
    "s_cbranch_vccz LdoneA%=\n\t"
    "s_add_u32 %[ct], %[ct], 1\n\t"
    "s_cmp_ge_u32 %[ct], 0x100000\n\t"
    "s_cbranch_scc1 Lfail%=\n\t"
    "global_load_dwordx4 v[40:43], %[ad], off sc1\n\t"
    "s_waitcnt vmcnt(1)\n\t"
    "v_xor_b32 v48, %[wt], v44\n\t"
    "v_xor_b32 v49, %[wt], v45\n\t"
    "v_or_b32 v48, v48, v49\n\t"
    "v_xor_b32 v49, %[wt], v46\n\t"
    "v_or_b32 v48, v48, v49\n\t"
    "v_xor_b32 v49, %[wt], v47\n\t"
    "v_or_b32 v48, v48, v49\n\t"
    "v_and_b32 v48, 0xffff, v48\n\t"
    "v_cmp_ne_u32 vcc, 0, v48\n\t"
    "s_cbranch_vccz LdoneB%=\n\t"
    "s_add_u32 %[ct], %[ct], 1\n\t"
    "s_cmp_ge_u32 %[ct], 0x100000\n\t"
    "s_cbranch_scc1 Lfail%=\n\t"
    "s_branch Lpoll%=\n"
    "LdoneA%=:\n\t"
    "s_waitcnt vmcnt(0)\n\t"             // retire the sibling load before reusing v44-47
    "v_and_b32 v44, 0xffff0000, v40\n\t"
    "v_and_b32 v45, 0xffff0000, v41\n\t"
    "v_and_b32 v46, 0xffff0000, v42\n\t"
    "v_and_b32 v47, 0xffff0000, v43\n\t"
    "ds_write_b128 %[la], v[44:47]\n\t"
    "s_branch Lend%=\n"
    "LdoneB%=:\n\t"
    "s_waitcnt vmcnt(0)\n\t"
    "v_and_b32 v40, 0xffff0000, v44\n\t"
    "v_and_b32 v41, 0xffff0000, v45\n\t"
    "v_and_b32 v42, 0xffff0000, v46\n\t"
    "v_and_b32 v43, 0xffff0000, v47\n\t"
    "ds_write_b128 %[la], v[40:43]\n\t"
    "s_branch Lend%=\n"
    "Lfail%=:\n\t"
    "s_waitcnt vmcnt(0)\n"
    "Lend%=:\n\t"
    "s_waitcnt lgkmcnt(0)"
    : [ct]"=&s"(cnt)
    : [ad]"v"(src), [wt]"v"(want), [la]"v"(lds_byte)
    : "v40","v41","v42","v43","v44","v45","v46","v47","v48","v49",
      "vcc","scc","memory");
  return cnt;
}

__global__ void __launch_bounds__(NTHR)
__attribute__((amdgpu_waves_per_eu(1, 2))) esn_persistent(
    const float* __restrict__ u,
    const float* __restrict__ W_in,
    const float* __restrict__ W_res,
    const int* __restrict__ washout_p,
    float* __restrict__ out,
    unsigned* __restrict__ ws)
{
  const int tid  = threadIdx.x;
  const int bid  = blockIdx.x;
  const int wave = tid >> 6;
  const int lane = tid & 63;
  const int row0 = bid * RPB + wave * 2;   // this wave owns rows row0, row0+1
  const int washout = washout_p[0];

  // ws layout (zeroed by hipMemsetAsync each launch):
  //   byte 1024+  : packed state, 2 parity buffers of 2048 u32
  //                 word[i] = (bf16(x[i]) << 16) | step_tag16   (0 == x0=0 @ t=0)
  unsigned* buf0 = ws + 256;        // byte offset 1024
  unsigned* buf1 = buf0 + NDIM;

  __shared__ __align__(16) float    x_lds[NDIM];
  __shared__ __align__(16) unsigned xpack_lds[RPB];  // block's 16 packed words (one 64B line)
  __shared__ __align__(16) float    xval_lds[RPB];   // block's 16 f32 values (out row)
  __shared__ int s_abort;
  if (tid == 0) s_abort = 0;

  // ---- W preload -> 64 fixed AGPRs (2 rows/wave). Plain loads feed W2A and
  // die immediately: no VGPR live range across the loop -> nothing to spill. ----
  {
    const f32x4* Wr0 = (const f32x4*)(W_res + (size_t)row0 * NDIM) + lane;
    const f32x4* Wr1 = (const f32x4*)(W_res + (size_t)(row0 + 1) * NDIM) + lane;
    W2A(Wr0[0 * 64], "a0",  "a1",  "a2",  "a3");
    W2A(Wr0[1 * 64], "a4",  "a5",  "a6",  "a7");
    W2A(Wr0[2 * 64], "a8",  "a9",  "a10", "a11");
    W2A(Wr0[3 * 64], "a12", "a13", "a14", "a15");
    W2A(Wr0[4 * 64], "a16", "a17", "a18", "a19");
    W2A(Wr0[5 * 64], "a20", "a21", "a22", "a23");
    W2A(Wr0[6 * 64], "a24", "a25", "a26", "a27");
    W2A(Wr0[7 * 64], "a28", "a29", "a30", "a31");
    W2A(Wr1[0 * 64], "a32", "a33", "a34", "a35");
    W2A(Wr1[1 * 64], "a36", "a37", "a38", "a39");
    W2A(Wr1[2 * 64], "a40", "a41", "a42", "a43");
    W2A(Wr1[3 * 64], "a44", "a45", "a46", "a47");
    W2A(Wr1[4 * 64], "a48", "a49", "a50", "a51");
    W2A(Wr1[5 * 64], "a52", "a53", "a54", "a55");
    W2A(Wr1[6 * 64], "a56", "a57", "a58", "a59");
    W2A(Wr1[7 * 64], "a60", "a61", "a62", "a63");
  }
  const float win0 = W_in[row0];
  const float win1 = W_in[row0 + 1];
  const unsigned lds_byte = (unsigned)(size_t)((f32x4*)x_lds + tid);

  for (int t = 0; t < TSTEPS; ++t) {
    // ---- fused poll+stage (depth-2 pipelined, in asm; writes x_lds[4tid..]) ----
    const u32x4* src = (const u32x4*)((t & 1) ? buf1 : buf0) + tid;
    const unsigned cnt = poll_stage(src, (unsigned)t, lds_byte);
    if (cnt >= (1u << 20)) s_abort = 1;   // uniform per wave (SGPR counter)
    const float ut = u[t];                // uniform, cached; hides under S_a
    __syncthreads();                      // S_a
    if (s_abort) return;                  // fail loudly instead of hanging

    // ---- 2 dot products per wave: W streamed from AGPRs, x from LDS. ----
    float a0 = 0.f, b0 = 0.f, a1 = 0.f, b1 = 0.f;
    const f32x4* x4v = (const f32x4*)x_lds + lane;
#define ESN_K(K, R0A, R0B, R0C, R0D, R1A, R1B, R1C, R1D, ACC0, ACC1) {       \
    f32x4 wv0, wv1;                                                          \
    A2V(wv0, R0A, R0B, R0C, R0D);                                            \
    A2V(wv1, R1A, R1B, R1C, R1D);                                            \
    const f32x4 xv = x4v[(K) * 64];                                          \
    ACC0 += wv0.x * xv.x; ACC0 += wv0.y * xv.y;                              \
    ACC0 += wv0.z * xv.z; ACC0 += wv0.w * xv.w;                              \
    ACC1 += wv1.x * xv.x; ACC1 += wv1.y * xv.y;                              \
    ACC1 += wv1.z * xv.z; ACC1 += wv1.w * xv.w; }
    ESN_K(0, "a0",  "a1",  "a2",  "a3",  "a32", "a33", "a34", "a35", a0, a1)
    ESN_K(1, "a4",  "a5",  "a6",  "a7",  "a36", "a37", "a38", "a39", b0, b1)
    ESN_K(2, "a8",  "a9",  "a10", "a11", "a40", "a41", "a42", "a43", a0, a1)
    ESN_K(3, "a12", "a13", "a14", "a15", "a44", "a45", "a46", "a47", b0, b1)
    ESN_K(4, "a16", "a17", "a18", "a19", "a48", "a49", "a50", "a51", a0, a1)
    ESN_K(5, "a20", "a21", "a22", "a23", "a52", "a53", "a54", "a55", b0, b1)
    ESN_K(6, "a24", "a25", "a26", "a27", "a56", "a57", "a58", "a59", a0, a1)
    ESN_K(7, "a28", "a29", "a30", "a31", "a60", "a61", "a62", "a63", b0, b1)
#undef ESN_K
    const float s0 = a0 + b0;
    const float s1 = a1 + b1;
    // 7-shfl reduce: fold 64->32 for both rows, route row1 to upper half, butterfly.
    const float c0 = s0 + __shfl_xor(s0, 32, 64);
    const float c1 = s1 + __shfl_xor(s1, 32, 64);
    float c = (lane < 32) ? c0 : c1;
#pragma unroll
    for (int off = 16; off > 0; off >>= 1) c += __shfl_xor(c, off, 64);

    if ((lane & 31) == 0) {               // lane 0 -> row0, lane 32 -> row1
      const float wi  = (lane == 0) ? win0 : win1;
      const float pre = wi * ut + c;
      const float e2  = __expf(2.0f * pre);            // tanh = 1 - 2/(e^2x + 1)
      const float th  = 1.0f - __fdividef(2.0f, e2 + 1.0f);
      const int   i   = wave * 2 + (lane >> 5);
      xval_lds[i] = th;
      const unsigned b  = __float_as_uint(th);
      const unsigned bf = (b + 0x7fffu + ((b >> 16) & 1u)) & 0xFFFF0000u; // RNE bf16
      xpack_lds[i] = bf | (unsigned)(t + 1);           // tag t+1 < 2^16
    }
    __syncthreads();                      // S_b

    // ---- publish: ONE 64B line per block (4 lanes x dwordx4), fire-and-forget ----
    if (tid < 8) {
      if (tid < 4) {
        u32x4* dst = (u32x4*)(((t + 1) & 1) ? buf1 : buf0) + bid * 4 + tid;
        st_x4_agent(dst, ((const u32x4*)xpack_lds)[tid]);
      } else if (t >= washout) {          // output row: plain cached stores (f32)
        float4* orow = (float4*)(out + (size_t)(t - washout) * NDIM) + bid * 4 + (tid - 4);
        const f32x4 vv = ((const f32x4*)xval_lds)[tid - 4];
        float4 v; v.x = vv.x; v.y = vv.y; v.z = vv.z; v.w = vv.w;
        *orow = v;
      }
    }
  }
}

extern "C" void kernel_launch(void* const* d_in, const int* in_sizes, int n_in,
                              void* d_out, int out_size, void* d_ws, size_t ws_size,
                              hipStream_t stream) {
  const float* u       = (const float*)d_in[0];
  const float* W_in    = (const float*)d_in[1];
  const float* W_res   = (const float*)d_in[2];
  const int*   washout = (const int*)d_in[3];
  float*       out     = (float*)d_out;

  // Zero both packed parity buffers (tag 0 == valid x0 = zeros). Captured in
  // the graph, so every replay starts from identical state.
  (void)hipMemsetAsync(d_ws, 0, 1024 + 2 * NDIM * 4, stream);

  esn_persistent<<<dim3(NBLK), dim3(NTHR), 0, stream>>>(
      u, W_in, W_res, washout, out, (unsigned*)d_ws);
}

// Round 9
// 16724.510 us; speedup vs baseline: 1.2071x; 1.2071x over previous
//
#include <hip/hip_runtime.h>

#define TSTEPS 8192
#define NDIM   2048
#define NBLK   128
#define NTHR   512
#define RPB    16     // rows per block = NDIM/NBLK
#define NREP   16     // state replicas: readers/line 512 -> 32, lines 128 -> 2048

typedef float    f32x4 __attribute__((ext_vector_type(4)));
typedef unsigned u32x4 __attribute__((ext_vector_type(4)));

// Agent-scope (device-coherent, sc1) ops — coherence point is the shared LLC.
__device__ __forceinline__ unsigned ld_u32_agent(const unsigned* p) {
  return __hip_atomic_load((unsigned*)p, __ATOMIC_RELAXED, __HIP_MEMORY_SCOPE_AGENT);
}
__device__ __forceinline__ void st_u32_agent(unsigned* p, unsigned v) {
  __hip_atomic_store(p, v, __ATOMIC_RELAXED, __HIP_MEMORY_SCOPE_AGENT);
}
// One 16B device-coherent load, completion fused in-asm.
__device__ __forceinline__ u32x4 ld_x4_agent(const u32x4* p) {
  u32x4 r;
  asm volatile("global_load_dwordx4 %0, %1, off sc1\n\ts_waitcnt vmcnt(0)"
               : "=v"(r) : "v"(p) : "memory");
  return r;
}
__device__ __forceinline__ void st_x4_agent(u32x4* p, u32x4 v) {
  asm volatile("global_store_dwordx4 %0, %1, off sc1" :: "v"(p), "v"(v) : "memory");
}
// W preload: value is an ASM OUTPUT (cannot be re-materialized as a reload).
__device__ __forceinline__ f32x4 ld_w_sync(const f32x4* p) {
  f32x4 r;
  asm volatile("global_load_dwordx4 %0, %1, off\n\ts_waitcnt vmcnt(0)"
               : "=v"(r) : "v"(p));
  return r;
}

__global__ void __launch_bounds__(NTHR, 1) esn_persistent(
    const float* __restrict__ u,
    const float* __restrict__ W_in,
    const float* __restrict__ W_res,
    const int* __restrict__ washout_p,
    float* __restrict__ out,
    unsigned* __restrict__ ws)
{
  const int tid  = threadIdx.x;
  const int bid  = blockIdx.x;
  const int wave = tid >> 6;
  const int lane = tid & 63;
  const int row0 = bid * RPB + wave * 2;   // this wave owns rows row0, row0+1
  const int washout = washout_p[0];

  // ws layout (zeroed by hipMemsetAsync each launch):
  //   u32[144]    : abort word (own line)
  //   byte 1024+  : NREP replicas x 2 parities x 2048 u32 packed state
  //                 word[i] = (bf16(x[i]) << 16) | step_tag16   (0 == x0=0 @ t=0)
  unsigned* abortw  = ws + 144;
  unsigned* repbase = ws + 256;       // byte offset 1024

  __shared__ __align__(16) float    x_lds[NDIM];
  __shared__ __align__(16) unsigned xpack_lds[RPB];  // block's 16 packed words (one 64B line)
  __shared__ __align__(16) float    xval_lds[RPB];   // block's 16 f32 values (out row)
  __shared__ int s_abort;
  if (tid == 0) s_abort = 0;

  // ---- W preload into 16 asm-defined f32x4 regs (2 rows/wave). The allocator
  // spills these to scratch anyway (rounds 3-8) — measured cost ~0 at current
  // sync latency; revisit after the sync floor moves. ----
  const f32x4* Wr0 = (const f32x4*)(W_res + (size_t)row0 * NDIM) + lane;
  const f32x4* Wr1 = (const f32x4*)(W_res + (size_t)(row0 + 1) * NDIM) + lane;
  const f32x4 w00 = ld_w_sync(Wr0 + 0 * 64), w01 = ld_w_sync(Wr0 + 1 * 64);
  const f32x4 w02 = ld_w_sync(Wr0 + 2 * 64), w03 = ld_w_sync(Wr0 + 3 * 64);
  const f32x4 w04 = ld_w_sync(Wr0 + 4 * 64), w05 = ld_w_sync(Wr0 + 5 * 64);
  const f32x4 w06 = ld_w_sync(Wr0 + 6 * 64), w07 = ld_w_sync(Wr0 + 7 * 64);
  const f32x4 w10 = ld_w_sync(Wr1 + 0 * 64), w11 = ld_w_sync(Wr1 + 1 * 64);
  const f32x4 w12 = ld_w_sync(Wr1 + 2 * 64), w13 = ld_w_sync(Wr1 + 3 * 64);
  const f32x4 w14 = ld_w_sync(Wr1 + 4 * 64), w15 = ld_w_sync(Wr1 + 5 * 64);
  const f32x4 w16 = ld_w_sync(Wr1 + 6 * 64), w17 = ld_w_sync(Wr1 + 7 * 64);
  const float win0 = W_in[row0];
  const float win1 = W_in[row0 + 1];

  // This block polls ONLY its private replica (bid & 15): 8 blocks per replica
  // -> 32 readers per 64B line instead of 512.
  unsigned* myrep0 = repbase + ((unsigned)(bid & (NREP - 1)) * 2) * NDIM;

  for (int t = 0; t < TSTEPS; ++t) {
    // ---- fused poll+stage: ONE dwordx4 per thread from the private replica,
    // retried until all 4 embedded tags == t. ----
    const u32x4* src = (const u32x4*)(myrep0 + (t & 1) * NDIM) + tid;
    const unsigned want = (unsigned)t;
    u32x4 r;
    bool ok;
    {
      unsigned g = 0;
      do {
        r = ld_x4_agent(src);
        ok = ((((r.x ^ want) | (r.y ^ want)) |
               ((r.z ^ want) | (r.w ^ want))) & 0xFFFFu) == 0u;
        if (!ok && ((++g & 255u) == 0u)) {
          if (ld_u32_agent(abortw) != 0u) break;
          if (g > (1u << 20)) { st_u32_agent(abortw, 1u); break; }
        }
      } while (!ok);
    }
    if (!ok) s_abort = 1;
    {
      f32x4 xv;   // unpack bf16 (high 16 bits) -> f32: one AND per element
      xv.x = __uint_as_float(r.x & 0xFFFF0000u);
      xv.y = __uint_as_float(r.y & 0xFFFF0000u);
      xv.z = __uint_as_float(r.z & 0xFFFF0000u);
      xv.w = __uint_as_float(r.w & 0xFFFF0000u);
      ((f32x4*)x_lds)[tid] = xv;
    }
    const float ut = u[t];                 // uniform, cached; hides under S_a
    __syncthreads();                       // S_a
    if (s_abort) return;                   // fail loudly instead of hanging

    // ---- 2 dot products per wave: x from LDS. ----
    float a0 = 0.f, b0 = 0.f, a1 = 0.f, b1 = 0.f;
    const f32x4* x4v = (const f32x4*)x_lds + lane;
#define ESN_DOT(WA, WB, K, A, B) { const f32x4 xv = x4v[(K) * 64];            \
      A += WA.x * xv.x; A += WA.y * xv.y; A += WA.z * xv.z; A += WA.w * xv.w; \
      B += WB.x * xv.x; B += WB.y * xv.y; B += WB.z * xv.z; B += WB.w * xv.w; }
    ESN_DOT(w00, w10, 0, a0, a1) ESN_DOT(w01, w11, 1, b0, b1)
    ESN_DOT(w02, w12, 2, a0, a1) ESN_DOT(w03, w13, 3, b0, b1)
    ESN_DOT(w04, w14, 4, a0, a1) ESN_DOT(w05, w15, 5, b0, b1)
    ESN_DOT(w06, w16, 6, a0, a1) ESN_DOT(w07, w17, 7, b0, b1)
#undef ESN_DOT
    const float s0 = a0 + b0;
    const float s1 = a1 + b1;
    // 7-shfl reduce: fold 64->32 for both rows, route row1 to upper half, butterfly.
    const float c0 = s0 + __shfl_xor(s0, 32, 64);
    const float c1 = s1 + __shfl_xor(s1, 32, 64);
    float c = (lane < 32) ? c0 : c1;
#pragma unroll
    for (int off = 16; off > 0; off >>= 1) c += __shfl_xor(c, off, 64);

    if ((lane & 31) == 0) {                // lane 0 -> row0, lane 32 -> row1
      const float wi  = (lane == 0) ? win0 : win1;
      const float pre = wi * ut + c;
      const float e2  = __expf(2.0f * pre);            // tanh = 1 - 2/(e^2x + 1)
      const float th  = 1.0f - __fdividef(2.0f, e2 + 1.0f);
      const int   i   = wave * 2 + (lane >> 5);
      xval_lds[i] = th;
      const unsigned b  = __float_as_uint(th);
      const unsigned bf = (b + 0x7fffu + ((b >> 16) & 1u)) & 0xFFFF0000u; // RNE bf16
      xpack_lds[i] = bf | (unsigned)(t + 1);           // tag t+1 < 2^16
    }
    __syncthreads();                       // S_b

    // ---- replicated publish: 64 threads store the block's 64B line into all
    // NREP replicas (one 16B store each, issue-parallel, fire-and-forget) ----
    if (tid < 4 * NREP) {
      const int rep = tid >> 2, seg = tid & 3;
      u32x4* dst = (u32x4*)(repbase + ((unsigned)(rep * 2 + ((t + 1) & 1)) * NDIM))
                   + bid * 4 + seg;
      st_x4_agent(dst, ((const u32x4*)xpack_lds)[seg]);
    } else if (tid >= 64 && tid < 68 && t >= washout) {  // output row (wave 1)
      float4* orow = (float4*)(out + (size_t)(t - washout) * NDIM) + bid * 4 + (tid - 64);
      const f32x4 vv = ((const f32x4*)xval_lds)[tid - 64];
      float4 v; v.x = vv.x; v.y = vv.y; v.z = vv.z; v.w = vv.w;
      *orow = v;
    }
  }
}

extern "C" void kernel_launch(void* const* d_in, const int* in_sizes, int n_in,
                              void* d_out, int out_size, void* d_ws, size_t ws_size,
                              hipStream_t stream) {
  const float* u       = (const float*)d_in[0];
  const float* W_in    = (const float*)d_in[1];
  const float* W_res   = (const float*)d_in[2];
  const int*   washout = (const int*)d_in[3];
  float*       out     = (float*)d_out;

  // Zero abort word + all replica parity buffers (tag 0 == valid x0 = zeros).
  // Captured in the graph, so every replay starts from identical state.
  (void)hipMemsetAsync(d_ws, 0, 1024 + NREP * 2 * NDIM * 4, stream);

  esn_persistent<<<dim3(NBLK), dim3(NTHR), 0, stream>>>(
      u, W_in, W_res, washout, out, (unsigned*)d_ws);
}